// Round 9
// baseline (88.692 us; speedup 1.0000x reference)
//
#include <hip/hip_runtime.h>
#include <hip/hip_bf16.h>

// Flash-attention forward, causal, B=2 H=16 S=2048 D=64, fp32 in/out.
// Round 9: BQ=128 (4 waves x 32 q-rows, 2 q-subcols share K/V LDS reads) +
// EXACT load balance: block (pair p, parity h in 0..3) does qtiles {15-p, p}
// on KV tiles kt%4==h -> every block 8-9 tile-units (max/mean 1.06), grid
// 1024 = 4 blocks/CU uniform. 2-buffer 32KB LDS + vmcnt(0) (r6-proven).
// bf16 partials, 4-way combine.

#define S_LEN 2048
#define D_DIM 64
#define BKV 64
#define NBH 32
#define NT128 16                      // 2048 / 128

typedef __bf16 bf16x8 __attribute__((ext_vector_type(8)));
typedef __bf16 bf16x4 __attribute__((ext_vector_type(4)));
typedef float f32x4 __attribute__((ext_vector_type(4)));

#define QSCALE 0.1803368801111243f   // (1/8) * log2(e)
#define NEG_MASK (-1e30f)            // masked scores
#define M_INIT  (-1e29f)             // m_run init: exp2(NEG_MASK - M_INIT) == 0
#define THRLOG2 11.5f                // defer-max threshold (log2 domain) ~ e^8

__device__ inline void glds16(const void* g, void* l) {
    __builtin_amdgcn_global_load_lds(
        (const __attribute__((address_space(1))) unsigned int*)g,
        (__attribute__((address_space(3))) unsigned int*)l, 16, 0, 0);
}

__device__ inline float m3(float a, float b, float c) {
    return fmaxf(fmaxf(a, b), c);    // clang fuses to v_max3_f32
}

// ---------------- fused convert kernel ----------------
// K: fp32->bf16 [s][d]. V: transposed to [bh][d][s] with per-64-col permutation
// (dest col c=(kk<<5)|(g<<3)|(b<<2)|i0 holds src j=(kk<<5)|(b<<4)|(g<<2)|i0) so
// a PV B-fragment is one contiguous 16B read.
__global__ __launch_bounds__(256)
void conv_fused_kernel(const float* __restrict__ k, const float* __restrict__ v,
                       __bf16* __restrict__ kb, __bf16* __restrict__ vt)
{
    __shared__ __bf16 T[64][72];
    const int bh = blockIdx.y, st = blockIdx.x;
    const int tid = threadIdx.x;
    const size_t base = (size_t)bh * S_LEN * D_DIM + (size_t)st * 64 * D_DIM;
    const float* kh = k + base;
    const float* vh = v + base;
    __bf16* kbh = kb + base;

#pragma unroll
    for (int it = 0; it < 2; ++it) {
        size_t i = ((size_t)tid + it * 256) * 8;
        float4 a = *(const float4*)(kh + i);
        float4 b = *(const float4*)(kh + i + 4);
        bf16x8 o;
        o[0] = (__bf16)a.x; o[1] = (__bf16)a.y; o[2] = (__bf16)a.z; o[3] = (__bf16)a.w;
        o[4] = (__bf16)b.x; o[5] = (__bf16)b.y; o[6] = (__bf16)b.z; o[7] = (__bf16)b.w;
        *(bf16x8*)(kbh + i) = o;
    }

#pragma unroll
    for (int it = 0; it < 4; ++it) {
        int idx = tid + it * 256;          // 64 s-rows x 16 float4
        int s = idx >> 4, c4 = idx & 15;
        float4 f = *(const float4*)(vh + s * D_DIM + c4 * 4);
        T[c4 * 4 + 0][s] = (__bf16)f.x;
        T[c4 * 4 + 1][s] = (__bf16)f.y;
        T[c4 * 4 + 2][s] = (__bf16)f.z;
        T[c4 * 4 + 3][s] = (__bf16)f.w;
    }
    __syncthreads();
    __bf16* vth = vt + (size_t)bh * D_DIM * S_LEN + st * 64;
#pragma unroll
    for (int it = 0; it < 2; ++it) {
        int idx = tid + it * 256;          // 64 d-rows x 8 chunks of 8
        int d = idx >> 3, c8 = idx & 7;
        int kk = c8 >> 2, g = c8 & 3;
        bf16x4 v0 = *(const bf16x4*)&T[d][kk * 32 + 4 * g];        // b=0
        bf16x4 v1 = *(const bf16x4*)&T[d][kk * 32 + 16 + 4 * g];   // b=1
        bf16x8 o;
        o[0] = v0[0]; o[1] = v0[1]; o[2] = v0[2]; o[3] = v0[3];
        o[4] = v1[0]; o[5] = v1[1]; o[6] = v1[2]; o[7] = v1[3];
        *(bf16x8*)(vth + (size_t)d * S_LEN + c8 * 8) = o;
    }
}

// ---------------- staging macro ----------------

#define STAGE(kt, buf)                                                          \
    {                                                                           \
        _Pragma("unroll")                                                       \
        for (int u = 0; u < 2; ++u) {                                           \
            glds16(kh + (size_t)((kt) * BKV + row_u[u]) * D_DIM + scol_u[u],    \
                   (__bf16*)&KL[buf][0][0] + (u * 4 + w) * 512);                \
            glds16(vh + (size_t)row_u[u] * S_LEN + (kt) * BKV + scol_u[u],      \
                   (__bf16*)&VL[buf][0][0] + (u * 4 + w) * 512);                \
        }                                                                       \
    }

// ---------------- split attention kernel: BQ=128, paired qtiles, 4-way parity ----

__global__ __launch_bounds__(256, 4)
void attn_fwd_split(const float* __restrict__ q, const __bf16* __restrict__ kb,
                    const __bf16* __restrict__ vt, __bf16* __restrict__ opart,
                    float* __restrict__ ml)
{
    __shared__ __bf16 KL[2][64][64];   // [buf][j][d], cols XOR-swizzled by ((j&7)<<3)
    __shared__ __bf16 VL[2][64][64];   // [buf][d][c], permuted cols, swizzled

    const int tid  = threadIdx.x;
    const int w    = tid >> 6;
    const int lane = tid & 63;
    const int l15  = lane & 15;
    const int lg   = lane >> 4;

    const int u0 = blockIdx.x;         // 0..31
    const int p  = u0 >> 2;            // pair 0..7
    const int h  = u0 & 3;             // KV parity (mod 4)
    const int bh = blockIdx.y;

    const float*  qh = q  + (size_t)bh * S_LEN * D_DIM;
    const __bf16* kh = kb + (size_t)bh * S_LEN * D_DIM;
    const __bf16* vh = vt + (size_t)bh * D_DIM * S_LEN;

    // staging decode (chunk c = u*4 + w; LDS elems e = c*512 + lane*8)
    int row_u[2], scol_u[2];
#pragma unroll
    for (int u = 0; u < 2; ++u) {
        int e = (u * 4 + w) * 512 + lane * 8;
        int r = e >> 6, c0 = e & 63;
        row_u[u]  = r;
        scol_u[u] = c0 ^ ((r & 7) << 3);
    }

    for (int chain = 0; chain < 2; ++chain) {
        const int T     = (chain == 0) ? (NT128 - 1 - p) : p;   // heavy first
        const int qbase = T * 128;
        // KV tiles 0..2T+1 of parity h (stride 4)
        const int cnt   = (2 * T + 1 >= h) ? ((2 * T + 1 - h) >> 2) + 1 : 0;

        // Q fragments (B operand), both q-subcols
        bf16x8 qf[2][2];
#pragma unroll
        for (int qc = 0; qc < 2; ++qc) {
            const int qrow = qbase + w * 32 + qc * 16 + l15;
            const float* qp = qh + (size_t)qrow * D_DIM + 8 * lg;
#pragma unroll
            for (int kk = 0; kk < 2; ++kk) {
                float4 a = *(const float4*)(qp + kk * 32);
                float4 b = *(const float4*)(qp + kk * 32 + 4);
                bf16x8 f;
                f[0] = (__bf16)(a.x * QSCALE); f[1] = (__bf16)(a.y * QSCALE);
                f[2] = (__bf16)(a.z * QSCALE); f[3] = (__bf16)(a.w * QSCALE);
                f[4] = (__bf16)(b.x * QSCALE); f[5] = (__bf16)(b.y * QSCALE);
                f[6] = (__bf16)(b.z * QSCALE); f[7] = (__bf16)(b.w * QSCALE);
                qf[qc][kk] = f;
            }
        }

        f32x4 acc[4][2] = {};
        float m_run[2]  = {M_INIT, M_INIT};
        float l_part[2] = {0.0f, 0.0f};

        if (chain == 1) __syncthreads();   // protect LDS reuse across chains
        if (cnt > 0) STAGE(h, 0);

        for (int i = 0; i < cnt; ++i) {
            const int kt  = h + 4 * i;
            const int cur = i & 1;
            asm volatile("s_waitcnt vmcnt(0)" ::: "memory");
            __builtin_amdgcn_s_barrier();
            if (i + 1 < cnt) STAGE(kt + 4, cur ^ 1);

            // K fragments once, shared by both q-subcols
            bf16x8 kf[4][2];
#pragma unroll
            for (int jt = 0; jt < 4; ++jt) {
                const int j  = jt * 16 + l15;
                const int sw = (j & 7) << 3;
                kf[jt][0] = *(const bf16x8*)&KL[cur][j][(8 * lg) ^ sw];
                kf[jt][1] = *(const bf16x8*)&KL[cur][j][(32 + 8 * lg) ^ sw];
            }

            // swapped QK^T: lane holds S[j][q], j = jt*16 + 4*lg + r
            f32x4 s0[4], s1[4];
            __builtin_amdgcn_s_setprio(1);
#pragma unroll
            for (int jt = 0; jt < 4; ++jt) {
                f32x4 c = {};
                c = __builtin_amdgcn_mfma_f32_16x16x32_bf16(kf[jt][0], qf[0][0], c, 0, 0, 0);
                c = __builtin_amdgcn_mfma_f32_16x16x32_bf16(kf[jt][1], qf[0][1], c, 0, 0, 0);
                s0[jt] = c;
                f32x4 d = {};
                d = __builtin_amdgcn_mfma_f32_16x16x32_bf16(kf[jt][0], qf[1][0], d, 0, 0, 0);
                d = __builtin_amdgcn_mfma_f32_16x16x32_bf16(kf[jt][1], qf[1][1], d, 0, 0, 0);
                s1[jt] = d;
            }
            __builtin_amdgcn_s_setprio(0);

            // causal mask: at most one tile per chain touches the diagonal
            // (kt in {2T, 2T+1}; stride 4 -> unique; it is the last tile)
            if (kt >= 2 * T) {
                const int dj = (kt - 2 * T) * 64;   // 0 or 64
                const int q0 = w * 32 + l15;        // qc=0 local q row
#pragma unroll
                for (int jt = 0; jt < 4; ++jt)
#pragma unroll
                    for (int r = 0; r < 4; ++r) {
                        const int jl = dj + jt * 16 + 4 * lg + r;
                        if (jl > q0)      s0[jt][r] = NEG_MASK;
                        if (jl > q0 + 16) s1[jt][r] = NEG_MASK;
                    }
            }

            // local row max per subcol
            float mxl0, mxl1;
            {
                float t0 = m3(s0[0][0], s0[0][1], s0[0][2]);
                float t1 = m3(s0[0][3], s0[1][0], s0[1][1]);
                float t2 = m3(s0[1][2], s0[1][3], s0[2][0]);
                float t3 = m3(s0[2][1], s0[2][2], s0[2][3]);
                float t4 = m3(s0[3][0], s0[3][1], s0[3][2]);
                mxl0 = m3(m3(t0, t1, t2), m3(t3, t4, s0[3][3]), NEG_MASK);
                float u1 = m3(s1[0][0], s1[0][1], s1[0][2]);
                float u2 = m3(s1[0][3], s1[1][0], s1[1][1]);
                float u3 = m3(s1[1][2], s1[1][3], s1[2][0]);
                float u4 = m3(s1[2][1], s1[2][2], s1[2][3]);
                float u5 = m3(s1[3][0], s1[3][1], s1[3][2]);
                mxl1 = m3(m3(u1, u2, u3), m3(u4, u5, s1[3][3]), NEG_MASK);
            }

            // defer-max: cross-lane reduce + rescale only on material growth
            if (__any((mxl0 > m_run[0] + THRLOG2) || (mxl1 > m_run[1] + THRLOG2))) {
                float mx0 = fmaxf(mxl0, __shfl_xor(mxl0, 16));
                mx0 = fmaxf(mx0, __shfl_xor(mx0, 32));
                float mx1 = fmaxf(mxl1, __shfl_xor(mxl1, 16));
                mx1 = fmaxf(mx1, __shfl_xor(mx1, 32));
                const float mt0 = fmaxf(m_run[0], mx0);
                const float mt1 = fmaxf(m_run[1], mx1);
                const float c0 = __builtin_amdgcn_exp2f(m_run[0] - mt0);
                const float c1 = __builtin_amdgcn_exp2f(m_run[1] - mt1);
                l_part[0] *= c0; m_run[0] = mt0;
                l_part[1] *= c1; m_run[1] = mt1;
                float ca0[4], ca1[4];
#pragma unroll
                for (int r = 0; r < 4; ++r) {
                    ca0[r] = __shfl(c0, 4 * lg + r);
                    ca1[r] = __shfl(c1, 4 * lg + r);
                }
#pragma unroll
                for (int dt = 0; dt < 4; ++dt)
#pragma unroll
                    for (int r = 0; r < 4; ++r) {
                        acc[dt][0][r] *= ca0[r];
                        acc[dt][1][r] *= ca1[r];
                    }
            }

            // P = exp2(s - m) -> bf16 A-fragments + per-lane partial sums
            float ps0 = 0.0f, ps1 = 0.0f;
            bf16x8 pa0[2], pa1[2];
#pragma unroll
            for (int kk = 0; kk < 2; ++kk)
#pragma unroll
                for (int i2 = 0; i2 < 4; ++i2) {
                    float ea = __builtin_amdgcn_exp2f(s0[2 * kk][i2] - m_run[0]);
                    float eb = __builtin_amdgcn_exp2f(s0[2 * kk + 1][i2] - m_run[0]);
                    ps0 += ea + eb;
                    pa0[kk][i2]     = (__bf16)ea;
                    pa0[kk][4 + i2] = (__bf16)eb;
                    float fa = __builtin_amdgcn_exp2f(s1[2 * kk][i2] - m_run[1]);
                    float fb = __builtin_amdgcn_exp2f(s1[2 * kk + 1][i2] - m_run[1]);
                    ps1 += fa + fb;
                    pa1[kk][i2]     = (__bf16)fa;
                    pa1[kk][4 + i2] = (__bf16)fb;
                }
            l_part[0] += ps0;
            l_part[1] += ps1;

            // PV: V fragments once, shared by both subcols
            __builtin_amdgcn_s_setprio(1);
#pragma unroll
            for (int dt = 0; dt < 4; ++dt) {
                const int d  = dt * 16 + l15;
                const int sw = (d & 7) << 3;
#pragma unroll
                for (int kk = 0; kk < 2; ++kk) {
                    bf16x8 vb = *(const bf16x8*)&VL[cur][d][(kk * 32 + 8 * lg) ^ sw];
                    acc[dt][0] = __builtin_amdgcn_mfma_f32_16x16x32_bf16(pa0[kk], vb, acc[dt][0], 0, 0, 0);
                    acc[dt][1] = __builtin_amdgcn_mfma_f32_16x16x32_bf16(pa1[kk], vb, acc[dt][1], 0, 0, 0);
                }
            }
            __builtin_amdgcn_s_setprio(0);
        }

        // epilogue: bf16 partials + per-row (m, l)
        __bf16* op  = opart + ((((size_t)bh * NT128 + T) * 4 + h) << 13);
        float*  mlp = ml    + ((((size_t)bh * NT128 + T) * 4 + h) << 8);
#pragma unroll
        for (int qc = 0; qc < 2; ++qc) {
            float lt = l_part[qc] + __shfl_xor(l_part[qc], 16);
            lt += __shfl_xor(lt, 32);
#pragma unroll
            for (int dt = 0; dt < 4; ++dt)
#pragma unroll
                for (int r = 0; r < 4; ++r)
                    op[(w * 32 + qc * 16 + 4 * lg + r) * 64 + dt * 16 + l15] =
                        (__bf16)acc[dt][qc][r];
            if (lg == 0) {
                mlp[w * 32 + qc * 16 + l15]       = m_run[qc];
                mlp[128 + w * 32 + qc * 16 + l15] = lt;
            }
        }
    }
}

// ---------------- combine kernel (4 partials per 128-row tile) ----------------

__global__ __launch_bounds__(256)
void combine_kernel(const __bf16* __restrict__ opart, const float* __restrict__ ml,
                    float* __restrict__ out)
{
    const int T   = blockIdx.x;
    const int bh  = blockIdx.y;
    const int tid = threadIdx.x;
    const int row = tid >> 1;          // 0..127
    const int c0  = (tid & 1) * 32;    // col base

    const float* mlp = ml + ((((size_t)bh * NT128 + T) * 4) << 8);
    float m[4], l[4];
#pragma unroll
    for (int hh = 0; hh < 4; ++hh) {
        m[hh] = mlp[hh * 256 + row];
        l[hh] = mlp[hh * 256 + 128 + row];
    }
    const float M = fmaxf(fmaxf(m[0], m[1]), fmaxf(m[2], m[3]));
    float wgt[4], L = 0.0f;
#pragma unroll
    for (int hh = 0; hh < 4; ++hh) {
        wgt[hh] = __builtin_amdgcn_exp2f(m[hh] - M);
        L += wgt[hh] * l[hh];
    }
    const float li = __builtin_amdgcn_rcpf(L);

    const __bf16* ob = opart + ((((size_t)bh * NT128 + T) * 4) << 13) + row * 64 + c0;
    float* oh = out + ((size_t)bh * S_LEN + T * 128 + row) * D_DIM + c0;

    float res[32];
#pragma unroll
    for (int j = 0; j < 32; ++j) res[j] = 0.0f;
#pragma unroll
    for (int hh = 0; hh < 4; ++hh) {
        const __bf16* o = ob + hh * 8192;
#pragma unroll
        for (int cc = 0; cc < 4; ++cc) {
            bf16x8 a = *(const bf16x8*)(o + cc * 8);
#pragma unroll
            for (int j = 0; j < 8; ++j)
                res[cc * 8 + j] += (float)a[j] * wgt[hh];
        }
    }
#pragma unroll
    for (int cc = 0; cc < 8; ++cc)
        ((float4*)oh)[cc] = make_float4(res[cc*4] * li, res[cc*4+1] * li,
                                        res[cc*4+2] * li, res[cc*4+3] * li);
}

// ---------------- r4-style single-pass kernel (mid fallback, ws >= 16MB) ----------------

__global__ __launch_bounds__(256)
void attn_fwd_glds(const float* __restrict__ q, const __bf16* __restrict__ kb,
                   const __bf16* __restrict__ vt, float* __restrict__ out)
{
    __shared__ __bf16 KL[3][64][64];
    __shared__ __bf16 VL[3][64][64];

    const int tid  = threadIdx.x;
    const int w    = tid >> 6;
    const int lane = tid & 63;
    const int l15  = lane & 15;
    const int lg   = lane >> 4;

    const int p  = blockIdx.x;
    const int bh = blockIdx.y;

    const float*  qh = q  + (size_t)bh * S_LEN * D_DIM;
    const __bf16* kh = kb + (size_t)bh * S_LEN * D_DIM;
    const __bf16* vh = vt + (size_t)bh * D_DIM * S_LEN;
    float*        oh = out + (size_t)bh * S_LEN * D_DIM;

    int row_u[2], scol_u[2];
#pragma unroll
    for (int u = 0; u < 2; ++u) {
        int e = (u * 4 + w) * 512 + lane * 8;
        int r = e >> 6, c0 = e & 63;
        row_u[u]  = r;
        scol_u[u] = c0 ^ ((r & 7) << 3);
    }

    for (int half = 0; half < 2; ++half) {
        const int qtile = (half == 0) ? (31 - p) : p;
        const int qbase = qtile * 64;
        const int nt    = qtile + 1;

        bf16x8 qf[2];
        {
            const int qrow = qbase + w * 16 + l15;
            const float* qp = qh + (size_t)qrow * D_DIM + 8 * lg;
#pragma unroll
            for (int kk = 0; kk < 2; ++kk) {
                float4 a = *(const float4*)(qp + kk * 32);
                float4 b = *(const float4*)(qp + kk * 32 + 4);
                bf16x8 f;
                f[0] = (__bf16)(a.x * QSCALE); f[1] = (__bf16)(a.y * QSCALE);
                f[2] = (__bf16)(a.z * QSCALE); f[3] = (__bf16)(a.w * QSCALE);
                f[4] = (__bf16)(b.x * QSCALE); f[5] = (__bf16)(b.y * QSCALE);
                f[6] = (__bf16)(b.z * QSCALE); f[7] = (__bf16)(b.w * QSCALE);
                qf[kk] = f;
            }
        }

        f32x4 acc[4] = {};
        float m_run = M_INIT;
        float l_part = 0.0f;

        if (half == 1) __syncthreads();
        STAGE(0, 0);
        if (nt > 1) STAGE(1, 1);

        for (int kt = 0; kt < nt; ++kt) {
            const int cur = kt % 3;
            if (kt + 1 < nt) { asm volatile("s_waitcnt vmcnt(4)" ::: "memory"); }
            else             { asm volatile("s_waitcnt vmcnt(0)" ::: "memory"); }
            __builtin_amdgcn_s_barrier();
            if (kt + 2 < nt) STAGE(kt + 2, (kt + 2) % 3);

            f32x4 s[4];
            __builtin_amdgcn_s_setprio(1);
#pragma unroll
            for (int jt = 0; jt < 4; ++jt) {
                const int j  = jt * 16 + l15;
                const int sw = (j & 7) << 3;
                f32x4 c = {};
#pragma unroll
                for (int kk = 0; kk < 2; ++kk) {
                    bf16x8 kf = *(const bf16x8*)&KL[cur][j][(kk * 32 + 8 * lg) ^ sw];
                    c = __builtin_amdgcn_mfma_f32_16x16x32_bf16(kf, qf[kk], c, 0, 0, 0);
                }
                s[jt] = c;
            }
            __builtin_amdgcn_s_setprio(0);

            if (kt == qtile) {
                const int qin = w * 16 + l15;
#pragma unroll
                for (int jt = 0; jt < 4; ++jt)
#pragma unroll
                    for (int r = 0; r < 4; ++r)
                        if (jt * 16 + 4 * lg + r > qin) s[jt][r] = NEG_MASK;
            }

            float t0 = m3(s[0][0], s[0][1], s[0][2]);
            float t1 = m3(s[0][3], s[1][0], s[1][1]);
            float t2 = m3(s[1][2], s[1][3], s[2][0]);
            float t3 = m3(s[2][1], s[2][2], s[2][3]);
            float t4 = m3(s[3][0], s[3][1], s[3][2]);
            float mxl = m3(m3(t0, t1, t2), m3(t3, t4, s[3][3]), NEG_MASK);

            if (__any(mxl > m_run + THRLOG2)) {
                float mx = fmaxf(mxl, __shfl_xor(mxl, 16));
                mx = fmaxf(mx, __shfl_xor(mx, 32));
                const float mt   = fmaxf(m_run, mx);
                const float corr = __builtin_amdgcn_exp2f(m_run - mt);
                l_part *= corr;
                m_run   = mt;
                float corr_a[4];
#pragma unroll
                for (int r = 0; r < 4; ++r) corr_a[r] = __shfl(corr, 4 * lg + r);
#pragma unroll
                for (int dt = 0; dt < 4; ++dt)
#pragma unroll
                    for (int r = 0; r < 4; ++r) acc[dt][r] *= corr_a[r];
            }

            float ps = 0.0f;
            float pe[4][4];
#pragma unroll
            for (int jt = 0; jt < 4; ++jt)
#pragma unroll
                for (int r = 0; r < 4; ++r) {
                    float e = __builtin_amdgcn_exp2f(s[jt][r] - m_run);
                    pe[jt][r] = e;
                    ps += e;
                }
            l_part += ps;

            bf16x8 pa[2];
#pragma unroll
            for (int kk = 0; kk < 2; ++kk)
#pragma unroll
                for (int i = 0; i < 4; ++i) {
                    pa[kk][i]     = (__bf16)pe[2 * kk][i];
                    pa[kk][4 + i] = (__bf16)pe[2 * kk + 1][i];
                }

            __builtin_amdgcn_s_setprio(1);
#pragma unroll
            for (int dt = 0; dt < 4; ++dt) {
                const int d  = dt * 16 + l15;
                const int sw = (d & 7) << 3;
#pragma unroll
                for (int kk = 0; kk < 2; ++kk) {
                    bf16x8 vb = *(const bf16x8*)&VL[cur][d][(kk * 32 + 8 * lg) ^ sw];
                    acc[dt] = __builtin_amdgcn_mfma_f32_16x16x32_bf16(pa[kk], vb, acc[dt], 0, 0, 0);
                }
            }
            __builtin_amdgcn_s_setprio(0);
        }

        float l_tot = l_part + __shfl_xor(l_part, 16);
        l_tot += __shfl_xor(l_tot, 32);
        float li_a[4];
#pragma unroll
        for (int r = 0; r < 4; ++r)
            li_a[r] = __builtin_amdgcn_rcpf(__shfl(l_tot, 4 * lg + r));
#pragma unroll
        for (int dt = 0; dt < 4; ++dt)
#pragma unroll
            for (int r = 0; r < 4; ++r)
                oh[(size_t)(qbase + w * 16 + 4 * lg + r) * D_DIM + dt * 16 + l15] =
                    acc[dt][r] * li_a[r];
    }
}
#undef STAGE

// ---------------- raw fallback (no-ws path) ----------------

#define PAD 72
__global__ __launch_bounds__(256)
void attn_fwd_fallback(const float* __restrict__ q, const float* __restrict__ k,
                       const float* __restrict__ v, float* __restrict__ out)
{
    __shared__ __bf16 Klds[64][PAD];
    __shared__ __bf16 Vt[D_DIM][PAD];
    __shared__ __bf16 Plds[4][16][PAD];

    const int tid  = threadIdx.x;
    const int w    = tid >> 6;
    const int lane = tid & 63;
    const int l15  = lane & 15;
    const int lg   = lane >> 4;

    const int qtile = blockIdx.x;
    const int bh    = blockIdx.y;
    const int qbase = qtile * 64;

    const size_t head_off = (size_t)bh * S_LEN * D_DIM;
    const float* qh = q + head_off;
    const float* kh = k + head_off;
    const float* vh = v + head_off;
    float*       oh = out + head_off;

    bf16x8 qf[2];
    {
        const int qrow = qbase + w * 16 + l15;
        const float* qp = qh + (size_t)qrow * D_DIM + 8 * lg;
#pragma unroll
        for (int c = 0; c < 2; ++c) {
            float4 a = *(const float4*)(qp + c * 32);
            float4 b = *(const float4*)(qp + c * 32 + 4);
            bf16x8 f;
            f[0] = (__bf16)(a.x * 0.125f); f[1] = (__bf16)(a.y * 0.125f);
            f[2] = (__bf16)(a.z * 0.125f); f[3] = (__bf16)(a.w * 0.125f);
            f[4] = (__bf16)(b.x * 0.125f); f[5] = (__bf16)(b.y * 0.125f);
            f[6] = (__bf16)(b.z * 0.125f); f[7] = (__bf16)(b.w * 0.125f);
            qf[c] = f;
        }
    }

    f32x4 acc[4] = {};
    float m_run[4], l_run[4];
#pragma unroll
    for (int r = 0; r < 4; ++r) { m_run[r] = -1e30f; l_run[r] = 0.0f; }

    const int nkv = qtile + 1;
    for (int kt = 0; kt < nkv; ++kt) {
        const int kv0 = kt * 64;
        __syncthreads();
#pragma unroll
        for (int it = 0; it < 4; ++it) {
            int idx = tid + it * 256;
            int row = idx >> 4;
            int c4  = idx & 15;
            float4 kf = *(const float4*)(kh + (size_t)(kv0 + row) * D_DIM + c4 * 4);
            __bf16* kd = &Klds[row][c4 * 4];
            kd[0] = (__bf16)kf.x; kd[1] = (__bf16)kf.y;
            kd[2] = (__bf16)kf.z; kd[3] = (__bf16)kf.w;
            float4 vf = *(const float4*)(vh + (size_t)(kv0 + row) * D_DIM + c4 * 4);
            Vt[c4 * 4 + 0][row] = (__bf16)vf.x;
            Vt[c4 * 4 + 1][row] = (__bf16)vf.y;
            Vt[c4 * 4 + 2][row] = (__bf16)vf.z;
            Vt[c4 * 4 + 3][row] = (__bf16)vf.w;
        }
        __syncthreads();

        f32x4 sfrag[4];
#pragma unroll
        for (int kc = 0; kc < 4; ++kc) {
            bf16x8 kf0 = *(const bf16x8*)&Klds[kc * 16 + l15][8 * lg];
            bf16x8 kf1 = *(const bf16x8*)&Klds[kc * 16 + l15][32 + 8 * lg];
            f32x4 c = {};
            c = __builtin_amdgcn_mfma_f32_16x16x32_bf16(qf[0], kf0, c, 0, 0, 0);
            c = __builtin_amdgcn_mfma_f32_16x16x32_bf16(qf[1], kf1, c, 0, 0, 0);
            sfrag[kc] = c;
        }

        if (kt == qtile) {
#pragma unroll
            for (int kc = 0; kc < 4; ++kc) {
                const int j = kv0 + kc * 16 + l15;
#pragma unroll
                for (int r = 0; r < 4; ++r) {
                    const int qrow = qbase + w * 16 + lg * 4 + r;
                    if (j > qrow) sfrag[kc][r] = -1e30f;
                }
            }
        }

        float mt[4], corr[4], ps[4];
#pragma unroll
        for (int r = 0; r < 4; ++r) {
            float mx = fmaxf(fmaxf(sfrag[0][r], sfrag[1][r]),
                             fmaxf(sfrag[2][r], sfrag[3][r]));
            mx = fmaxf(mx, __shfl_xor(mx, 1));
            mx = fmaxf(mx, __shfl_xor(mx, 2));
            mx = fmaxf(mx, __shfl_xor(mx, 4));
            mx = fmaxf(mx, __shfl_xor(mx, 8));
            mt[r]   = fmaxf(m_run[r], mx);
            corr[r] = __expf(m_run[r] - mt[r]);
            ps[r]   = 0.0f;
        }
#pragma unroll
        for (int kc = 0; kc < 4; ++kc) {
#pragma unroll
            for (int r = 0; r < 4; ++r) {
                float pp = __expf(sfrag[kc][r] - mt[r]);
                ps[r] += pp;
                Plds[w][lg * 4 + r][kc * 16 + l15] = (__bf16)pp;
            }
        }
#pragma unroll
        for (int r = 0; r < 4; ++r) {
            ps[r] += __shfl_xor(ps[r], 1);
            ps[r] += __shfl_xor(ps[r], 2);
            ps[r] += __shfl_xor(ps[r], 4);
            ps[r] += __shfl_xor(ps[r], 8);
            l_run[r] = l_run[r] * corr[r] + ps[r];
            m_run[r] = mt[r];
        }
#pragma unroll
        for (int dt = 0; dt < 4; ++dt)
#pragma unroll
            for (int r = 0; r < 4; ++r)
                acc[dt][r] *= corr[r];

#pragma unroll
        for (int kk = 0; kk < 2; ++kk) {
            bf16x8 pf = *(const bf16x8*)&Plds[w][l15][kk * 32 + 8 * lg];
#pragma unroll
            for (int dt = 0; dt < 4; ++dt) {
                bf16x8 vf = *(const bf16x8*)&Vt[dt * 16 + l15][kk * 32 + 8 * lg];
                acc[dt] = __builtin_amdgcn_mfma_f32_16x16x32_bf16(pf, vf, acc[dt], 0, 0, 0);
            }
        }
    }

#pragma unroll
    for (int dt = 0; dt < 4; ++dt) {
#pragma unroll
        for (int r = 0; r < 4; ++r) {
            const int qrow = qbase + w * 16 + lg * 4 + r;
            oh[(size_t)qrow * D_DIM + dt * 16 + l15] = acc[dt][r] / l_run[r];
        }
    }
}

extern "C" void kernel_launch(void* const* d_in, const int* in_sizes, int n_in,
                              void* d_out, int out_size, void* d_ws, size_t ws_size,
                              hipStream_t stream) {
    const float* q = (const float*)d_in[0];
    const float* k = (const float*)d_in[1];
    const float* v = (const float*)d_in[2];
    float* out = (float*)d_out;

    const size_t kv_elems   = (size_t)NBH * S_LEN * D_DIM;          // 4,194,304
    const size_t conv_bytes = kv_elems * 2 * sizeof(__bf16);        // 16 MiB
    const size_t op_bytes   = (size_t)NBH * NT128 * 4 * 8192 * 2;   // 32 MiB (bf16)
    const size_t ml_bytes   = (size_t)NBH * NT128 * 4 * 256 * 4;    // 2 MiB

    if (ws_size >= conv_bytes + op_bytes + ml_bytes) {
        __bf16* kb = (__bf16*)d_ws;
        __bf16* vt = kb + kv_elems;
        __bf16* opart = (__bf16*)((char*)d_ws + conv_bytes);
        float*  ml    = (float*)((char*)d_ws + conv_bytes + op_bytes);
        conv_fused_kernel<<<dim3(S_LEN / 64, NBH), dim3(256), 0, stream>>>(k, v, kb, vt);
        attn_fwd_split<<<dim3(32, NBH), dim3(256), 0, stream>>>(q, kb, vt, opart, ml);
        combine_kernel<<<dim3(NT128, NBH), dim3(256), 0, stream>>>(opart, ml, out);
    } else if (ws_size >= conv_bytes) {
        __bf16* kb = (__bf16*)d_ws;
        __bf16* vt = kb + kv_elems;
        conv_fused_kernel<<<dim3(S_LEN / 64, NBH), dim3(256), 0, stream>>>(k, v, kb, vt);
        attn_fwd_glds<<<dim3(16, NBH), dim3(256), 0, stream>>>(q, kb, vt, out);
    } else {
        attn_fwd_fallback<<<dim3(S_LEN / 64, NBH), dim3(256), 0, stream>>>(q, k, v, out);
    }
}

// Round 10
// 59.946 us; speedup vs baseline: 1.4795x; 1.4795x over previous
//
#include <hip/hip_runtime.h>
#include <hip/hip_bf16.h>

// Flash-attention forward, causal, B=2 H=16 S=2048 D=64, fp32 in/out.
// Round 10: r4's proven pipeline (3-buffer LDS, depth-2 prefetch, counted
// vmcnt(4)) + BQ=128 dual-subcol (halved LDS reads per unit work) + uniform
// 2-way KV-parity pairing: block (p,h,bh) does qtile chains {15-p, p} on KV
// tiles kt%2==h -> exactly 17 tiles/block, grid 512 = 2 blocks/CU.
// Blocked coalesced bf16 partials + cheap combine.

#define S_LEN 2048
#define D_DIM 64
#define BKV 64
#define NBH 32
#define NT128 16                      // 2048 / 128

typedef __bf16 bf16x8 __attribute__((ext_vector_type(8)));
typedef __bf16 bf16x4 __attribute__((ext_vector_type(4)));
typedef float f32x4 __attribute__((ext_vector_type(4)));

#define QSCALE 0.1803368801111243f   // (1/8) * log2(e)
#define NEG_MASK (-1e30f)            // masked scores
#define M_INIT  (-1e29f)             // m_run init: exp2(NEG_MASK - M_INIT) == 0
#define THRLOG2 11.5f                // defer-max threshold (log2 domain) ~ e^8

__device__ inline void glds16(const void* g, void* l) {
    __builtin_amdgcn_global_load_lds(
        (const __attribute__((address_space(1))) unsigned int*)g,
        (__attribute__((address_space(3))) unsigned int*)l, 16, 0, 0);
}

__device__ inline float m3(float a, float b, float c) {
    return fmaxf(fmaxf(a, b), c);    // clang fuses to v_max3_f32
}

// ---------------- fused convert kernel ----------------
// K: fp32->bf16 [s][d]. V: transposed to [bh][d][s] with per-64-col permutation
// (dest col c=(kk<<5)|(g<<3)|(b<<2)|i0 holds src j=(kk<<5)|(b<<4)|(g<<2)|i0) so
// a PV B-fragment is one contiguous 16B read.
__global__ __launch_bounds__(256)
void conv_fused_kernel(const float* __restrict__ k, const float* __restrict__ v,
                       __bf16* __restrict__ kb, __bf16* __restrict__ vt)
{
    __shared__ __bf16 T[64][72];
    const int bh = blockIdx.y, st = blockIdx.x;
    const int tid = threadIdx.x;
    const size_t base = (size_t)bh * S_LEN * D_DIM + (size_t)st * 64 * D_DIM;
    const float* kh = k + base;
    const float* vh = v + base;
    __bf16* kbh = kb + base;

#pragma unroll
    for (int it = 0; it < 2; ++it) {
        size_t i = ((size_t)tid + it * 256) * 8;
        float4 a = *(const float4*)(kh + i);
        float4 b = *(const float4*)(kh + i + 4);
        bf16x8 o;
        o[0] = (__bf16)a.x; o[1] = (__bf16)a.y; o[2] = (__bf16)a.z; o[3] = (__bf16)a.w;
        o[4] = (__bf16)b.x; o[5] = (__bf16)b.y; o[6] = (__bf16)b.z; o[7] = (__bf16)b.w;
        *(bf16x8*)(kbh + i) = o;
    }

#pragma unroll
    for (int it = 0; it < 4; ++it) {
        int idx = tid + it * 256;          // 64 s-rows x 16 float4
        int s = idx >> 4, c4 = idx & 15;
        float4 f = *(const float4*)(vh + s * D_DIM + c4 * 4);
        T[c4 * 4 + 0][s] = (__bf16)f.x;
        T[c4 * 4 + 1][s] = (__bf16)f.y;
        T[c4 * 4 + 2][s] = (__bf16)f.z;
        T[c4 * 4 + 3][s] = (__bf16)f.w;
    }
    __syncthreads();
    __bf16* vth = vt + (size_t)bh * D_DIM * S_LEN + st * 64;
#pragma unroll
    for (int it = 0; it < 2; ++it) {
        int idx = tid + it * 256;          // 64 d-rows x 8 chunks of 8
        int d = idx >> 3, c8 = idx & 7;
        int kk = c8 >> 2, g = c8 & 3;
        bf16x4 v0 = *(const bf16x4*)&T[d][kk * 32 + 4 * g];        // b=0
        bf16x4 v1 = *(const bf16x4*)&T[d][kk * 32 + 16 + 4 * g];   // b=1
        bf16x8 o;
        o[0] = v0[0]; o[1] = v0[1]; o[2] = v0[2]; o[3] = v0[3];
        o[4] = v1[0]; o[5] = v1[1]; o[6] = v1[2]; o[7] = v1[3];
        *(bf16x8*)(vth + (size_t)d * S_LEN + c8 * 8) = o;
    }
}

// ---------------- staging macro ----------------

#define STAGE(kt, buf)                                                          \
    {                                                                           \
        _Pragma("unroll")                                                       \
        for (int u = 0; u < 2; ++u) {                                           \
            glds16(kh + (size_t)((kt) * BKV + row_u[u]) * D_DIM + scol_u[u],    \
                   (__bf16*)&KL[buf][0][0] + (u * 4 + w) * 512);                \
            glds16(vh + (size_t)row_u[u] * S_LEN + (kt) * BKV + scol_u[u],      \
                   (__bf16*)&VL[buf][0][0] + (u * 4 + w) * 512);                \
        }                                                                       \
    }

// ---------------- split attention kernel: BQ=128, pairing, 2-way parity ------

__global__ __launch_bounds__(256)
void attn_fwd_split(const float* __restrict__ q, const __bf16* __restrict__ kb,
                    const __bf16* __restrict__ vt, __bf16* __restrict__ opart,
                    float* __restrict__ ml)
{
    __shared__ __bf16 KL[3][64][64];   // [buf][j][d], cols XOR-swizzled by ((j&7)<<3)
    __shared__ __bf16 VL[3][64][64];   // [buf][d][c], permuted cols, swizzled

    const int tid  = threadIdx.x;
    const int w    = tid >> 6;
    const int lane = tid & 63;
    const int l15  = lane & 15;
    const int lg   = lane >> 4;

    const int u0 = blockIdx.x;         // 0..15
    const int p  = u0 >> 1;            // pair 0..7
    const int h  = u0 & 1;             // KV parity
    const int bh = blockIdx.y;

    const float*  qh = q  + (size_t)bh * S_LEN * D_DIM;
    const __bf16* kh = kb + (size_t)bh * S_LEN * D_DIM;
    const __bf16* vh = vt + (size_t)bh * D_DIM * S_LEN;

    // staging decode (chunk c = u*4 + w; LDS elems e = c*512 + lane*8)
    int row_u[2], scol_u[2];
#pragma unroll
    for (int u = 0; u < 2; ++u) {
        int e = (u * 4 + w) * 512 + lane * 8;
        int r = e >> 6, c0 = e & 63;
        row_u[u]  = r;
        scol_u[u] = c0 ^ ((r & 7) << 3);
    }

    for (int chain = 0; chain < 2; ++chain) {
        const int T     = (chain == 0) ? (NT128 - 1 - p) : p;
        const int qbase = T * 128;
        const int cnt   = T + 1;       // parity-h tiles among 0..2T+1

        // Q fragments (B operand), both q-subcols
        bf16x8 qf[2][2];
#pragma unroll
        for (int qc = 0; qc < 2; ++qc) {
            const int qrow = qbase + w * 32 + qc * 16 + l15;
            const float* qp = qh + (size_t)qrow * D_DIM + 8 * lg;
#pragma unroll
            for (int kk = 0; kk < 2; ++kk) {
                float4 a = *(const float4*)(qp + kk * 32);
                float4 b = *(const float4*)(qp + kk * 32 + 4);
                bf16x8 f;
                f[0] = (__bf16)(a.x * QSCALE); f[1] = (__bf16)(a.y * QSCALE);
                f[2] = (__bf16)(a.z * QSCALE); f[3] = (__bf16)(a.w * QSCALE);
                f[4] = (__bf16)(b.x * QSCALE); f[5] = (__bf16)(b.y * QSCALE);
                f[6] = (__bf16)(b.z * QSCALE); f[7] = (__bf16)(b.w * QSCALE);
                qf[qc][kk] = f;
            }
        }

        f32x4 acc[4][2] = {};
        float m_run[2]  = {M_INIT, M_INIT};
        float l_part[2] = {0.0f, 0.0f};

        if (chain == 1) __syncthreads();   // protect LDS reuse across chains
        STAGE(h, 0);
        if (cnt > 1) STAGE(h + 2, 1);

        for (int i = 0; i < cnt; ++i) {
            const int cur = i % 3;
            if (i + 1 < cnt) { asm volatile("s_waitcnt vmcnt(4)" ::: "memory"); }
            else             { asm volatile("s_waitcnt vmcnt(0)" ::: "memory"); }
            __builtin_amdgcn_s_barrier();
            if (i + 2 < cnt) STAGE(h + 2 * (i + 2), (i + 2) % 3);

            // K fragments once, shared by both q-subcols
            bf16x8 kf[4][2];
#pragma unroll
            for (int jt = 0; jt < 4; ++jt) {
                const int j  = jt * 16 + l15;
                const int sw = (j & 7) << 3;
                kf[jt][0] = *(const bf16x8*)&KL[cur][j][(8 * lg) ^ sw];
                kf[jt][1] = *(const bf16x8*)&KL[cur][j][(32 + 8 * lg) ^ sw];
            }

            // swapped QK^T: lane holds S[j][q], j = jt*16 + 4*lg + r
            f32x4 s0[4], s1[4];
            __builtin_amdgcn_s_setprio(1);
#pragma unroll
            for (int jt = 0; jt < 4; ++jt) {
                f32x4 c = {};
                c = __builtin_amdgcn_mfma_f32_16x16x32_bf16(kf[jt][0], qf[0][0], c, 0, 0, 0);
                c = __builtin_amdgcn_mfma_f32_16x16x32_bf16(kf[jt][1], qf[0][1], c, 0, 0, 0);
                s0[jt] = c;
                f32x4 d = {};
                d = __builtin_amdgcn_mfma_f32_16x16x32_bf16(kf[jt][0], qf[1][0], d, 0, 0, 0);
                d = __builtin_amdgcn_mfma_f32_16x16x32_bf16(kf[jt][1], qf[1][1], d, 0, 0, 0);
                s1[jt] = d;
            }
            __builtin_amdgcn_s_setprio(0);

            // causal mask: diagonal tile kt=2T+h is the chain's LAST tile.
            // global j = (2T+h)*64 + jl0, global q = T*128 + qloc ->
            // mask iff h*64 + jl0 > qloc.
            if (i == cnt - 1) {
                const int q0 = w * 32 + l15;       // qc=0 local q row
#pragma unroll
                for (int jt = 0; jt < 4; ++jt)
#pragma unroll
                    for (int r = 0; r < 4; ++r) {
                        const int jl = h * 64 + jt * 16 + 4 * lg + r;
                        if (jl > q0)      s0[jt][r] = NEG_MASK;
                        if (jl > q0 + 16) s1[jt][r] = NEG_MASK;
                    }
            }

            // local row max per subcol
            float mxl0, mxl1;
            {
                float t0 = m3(s0[0][0], s0[0][1], s0[0][2]);
                float t1 = m3(s0[0][3], s0[1][0], s0[1][1]);
                float t2 = m3(s0[1][2], s0[1][3], s0[2][0]);
                float t3 = m3(s0[2][1], s0[2][2], s0[2][3]);
                float t4 = m3(s0[3][0], s0[3][1], s0[3][2]);
                mxl0 = m3(m3(t0, t1, t2), m3(t3, t4, s0[3][3]), NEG_MASK);
                float u1 = m3(s1[0][0], s1[0][1], s1[0][2]);
                float u2 = m3(s1[0][3], s1[1][0], s1[1][1]);
                float u3 = m3(s1[1][2], s1[1][3], s1[2][0]);
                float u4 = m3(s1[2][1], s1[2][2], s1[2][3]);
                float u5 = m3(s1[3][0], s1[3][1], s1[3][2]);
                mxl1 = m3(m3(u1, u2, u3), m3(u4, u5, s1[3][3]), NEG_MASK);
            }

            // defer-max: cross-lane reduce + rescale only on material growth
            if (__any((mxl0 > m_run[0] + THRLOG2) || (mxl1 > m_run[1] + THRLOG2))) {
                float mx0 = fmaxf(mxl0, __shfl_xor(mxl0, 16));
                mx0 = fmaxf(mx0, __shfl_xor(mx0, 32));
                float mx1 = fmaxf(mxl1, __shfl_xor(mxl1, 16));
                mx1 = fmaxf(mx1, __shfl_xor(mx1, 32));
                const float mt0 = fmaxf(m_run[0], mx0);
                const float mt1 = fmaxf(m_run[1], mx1);
                const float c0 = __builtin_amdgcn_exp2f(m_run[0] - mt0);
                const float c1 = __builtin_amdgcn_exp2f(m_run[1] - mt1);
                l_part[0] *= c0; m_run[0] = mt0;
                l_part[1] *= c1; m_run[1] = mt1;
                float ca0[4], ca1[4];
#pragma unroll
                for (int r = 0; r < 4; ++r) {
                    ca0[r] = __shfl(c0, 4 * lg + r);
                    ca1[r] = __shfl(c1, 4 * lg + r);
                }
#pragma unroll
                for (int dt = 0; dt < 4; ++dt)
#pragma unroll
                    for (int r = 0; r < 4; ++r) {
                        acc[dt][0][r] *= ca0[r];
                        acc[dt][1][r] *= ca1[r];
                    }
            }

            // P = exp2(s - m) -> bf16 A-fragments + per-lane partial sums
            float ps0 = 0.0f, ps1 = 0.0f;
            bf16x8 pa0[2], pa1[2];
#pragma unroll
            for (int kk = 0; kk < 2; ++kk)
#pragma unroll
                for (int i2 = 0; i2 < 4; ++i2) {
                    float ea = __builtin_amdgcn_exp2f(s0[2 * kk][i2] - m_run[0]);
                    float eb = __builtin_amdgcn_exp2f(s0[2 * kk + 1][i2] - m_run[0]);
                    ps0 += ea + eb;
                    pa0[kk][i2]     = (__bf16)ea;
                    pa0[kk][4 + i2] = (__bf16)eb;
                    float fa = __builtin_amdgcn_exp2f(s1[2 * kk][i2] - m_run[1]);
                    float fb = __builtin_amdgcn_exp2f(s1[2 * kk + 1][i2] - m_run[1]);
                    ps1 += fa + fb;
                    pa1[kk][i2]     = (__bf16)fa;
                    pa1[kk][4 + i2] = (__bf16)fb;
                }
            l_part[0] += ps0;
            l_part[1] += ps1;

            // PV: V fragments once, shared by both subcols
            __builtin_amdgcn_s_setprio(1);
#pragma unroll
            for (int dt = 0; dt < 4; ++dt) {
                const int d  = dt * 16 + l15;
                const int sw = (d & 7) << 3;
#pragma unroll
                for (int kk = 0; kk < 2; ++kk) {
                    bf16x8 vb = *(const bf16x8*)&VL[cur][d][(kk * 32 + 8 * lg) ^ sw];
                    acc[dt][0] = __builtin_amdgcn_mfma_f32_16x16x32_bf16(pa0[kk], vb, acc[dt][0], 0, 0, 0);
                    acc[dt][1] = __builtin_amdgcn_mfma_f32_16x16x32_bf16(pa1[kk], vb, acc[dt][1], 0, 0, 0);
                }
            }
            __builtin_amdgcn_s_setprio(0);
        }

        // epilogue: blocked coalesced bf16 partials (lane-contiguous 64B)
        // value (dt, qc, r) at op[tid*32 + dt*8 + qc*4 + r]
        float lt[2];
#pragma unroll
        for (int qc = 0; qc < 2; ++qc) {
            lt[qc] = l_part[qc] + __shfl_xor(l_part[qc], 16);
            lt[qc] += __shfl_xor(lt[qc], 32);
        }
        __bf16* op = opart + ((((size_t)bh * NT128 + T) * 2 + h) << 13) + (size_t)tid * 32;
#pragma unroll
        for (int dt = 0; dt < 4; ++dt) {
            bf16x8 wv;
#pragma unroll
            for (int r = 0; r < 4; ++r) {
                wv[r]     = (__bf16)acc[dt][0][r];
                wv[4 + r] = (__bf16)acc[dt][1][r];
            }
            *(bf16x8*)(op + dt * 8) = wv;
        }
        float* mlp = ml + ((((size_t)bh * NT128 + T) * 2 + h) << 8);
        if (lg == 0) {
#pragma unroll
            for (int qc = 0; qc < 2; ++qc) {
                mlp[w * 32 + qc * 16 + l15]       = m_run[qc];
                mlp[128 + w * 32 + qc * 16 + l15] = lt[qc];
            }
        }
    }
}

// ---------------- combine kernel (2 partials per 128-row tile) ----------------

__global__ __launch_bounds__(256)
void combine_kernel(const __bf16* __restrict__ opart, const float* __restrict__ ml,
                    float* __restrict__ out)
{
    const int T   = blockIdx.x;
    const int bh  = blockIdx.y;
    const int tid = threadIdx.x;
    const int w    = tid >> 6;
    const int lane = tid & 63;
    const int l15  = lane & 15;
    const int lg   = lane >> 4;

    const size_t b0 = ((size_t)bh * NT128 + T) * 2;
    const __bf16* o0 = opart + (b0 << 13) + (size_t)tid * 32;
    const __bf16* o1 = o0 + 8192;
    const float* ml0 = ml + (b0 << 8);
    const float* ml1 = ml0 + 256;

    // per-row merge weights (8 rows per thread: qc in {0,1}, r in 0..3)
    float w0a[2][4], w1a[2][4];
#pragma unroll
    for (int qc = 0; qc < 2; ++qc)
#pragma unroll
        for (int r = 0; r < 4; ++r) {
            const int row = w * 32 + qc * 16 + 4 * lg + r;
            const float m0 = ml0[row], l0 = ml0[128 + row];
            const float m1 = ml1[row], l1 = ml1[128 + row];
            const float M  = fmaxf(m0, m1);
            const float e0 = __builtin_amdgcn_exp2f(m0 - M);
            const float e1 = __builtin_amdgcn_exp2f(m1 - M);
            const float li = __builtin_amdgcn_rcpf(e0 * l0 + e1 * l1);
            w0a[qc][r] = e0 * li;
            w1a[qc][r] = e1 * li;
        }

    float* oh = out + ((size_t)bh * S_LEN + T * 128) * D_DIM;
#pragma unroll
    for (int dt = 0; dt < 4; ++dt) {
        bf16x8 a = *(const bf16x8*)(o0 + dt * 8);
        bf16x8 b = *(const bf16x8*)(o1 + dt * 8);
#pragma unroll
        for (int qc = 0; qc < 2; ++qc)
#pragma unroll
            for (int r = 0; r < 4; ++r) {
                const int row = w * 32 + qc * 16 + 4 * lg + r;
                const int j   = qc * 4 + r;
                oh[(size_t)row * D_DIM + dt * 16 + l15] =
                    (float)a[j] * w0a[qc][r] + (float)b[j] * w1a[qc][r];
            }
    }
}

// ---------------- r4-style single-pass kernel (mid fallback, ws >= 16MB) ----------------

__global__ __launch_bounds__(256)
void attn_fwd_glds(const float* __restrict__ q, const __bf16* __restrict__ kb,
                   const __bf16* __restrict__ vt, float* __restrict__ out)
{
    __shared__ __bf16 KL[3][64][64];
    __shared__ __bf16 VL[3][64][64];

    const int tid  = threadIdx.x;
    const int w    = tid >> 6;
    const int lane = tid & 63;
    const int l15  = lane & 15;
    const int lg   = lane >> 4;

    const int p  = blockIdx.x;
    const int bh = blockIdx.y;

    const float*  qh = q  + (size_t)bh * S_LEN * D_DIM;
    const __bf16* kh = kb + (size_t)bh * S_LEN * D_DIM;
    const __bf16* vh = vt + (size_t)bh * D_DIM * S_LEN;
    float*        oh = out + (size_t)bh * S_LEN * D_DIM;

    int row_u[2], scol_u[2];
#pragma unroll
    for (int u = 0; u < 2; ++u) {
        int e = (u * 4 + w) * 512 + lane * 8;
        int r = e >> 6, c0 = e & 63;
        row_u[u]  = r;
        scol_u[u] = c0 ^ ((r & 7) << 3);
    }

    for (int half = 0; half < 2; ++half) {
        const int qtile = (half == 0) ? (31 - p) : p;
        const int qbase = qtile * 64;
        const int nt    = qtile + 1;

        bf16x8 qf[2];
        {
            const int qrow = qbase + w * 16 + l15;
            const float* qp = qh + (size_t)qrow * D_DIM + 8 * lg;
#pragma unroll
            for (int kk = 0; kk < 2; ++kk) {
                float4 a = *(const float4*)(qp + kk * 32);
                float4 b = *(const float4*)(qp + kk * 32 + 4);
                bf16x8 f;
                f[0] = (__bf16)(a.x * QSCALE); f[1] = (__bf16)(a.y * QSCALE);
                f[2] = (__bf16)(a.z * QSCALE); f[3] = (__bf16)(a.w * QSCALE);
                f[4] = (__bf16)(b.x * QSCALE); f[5] = (__bf16)(b.y * QSCALE);
                f[6] = (__bf16)(b.z * QSCALE); f[7] = (__bf16)(b.w * QSCALE);
                qf[kk] = f;
            }
        }

        f32x4 acc[4] = {};
        float m_run = M_INIT;
        float l_part = 0.0f;

        if (half == 1) __syncthreads();
        STAGE(0, 0);
        if (nt > 1) STAGE(1, 1);

        for (int kt = 0; kt < nt; ++kt) {
            const int cur = kt % 3;
            if (kt + 1 < nt) { asm volatile("s_waitcnt vmcnt(4)" ::: "memory"); }
            else             { asm volatile("s_waitcnt vmcnt(0)" ::: "memory"); }
            __builtin_amdgcn_s_barrier();
            if (kt + 2 < nt) STAGE(kt + 2, (kt + 2) % 3);

            f32x4 s[4];
            __builtin_amdgcn_s_setprio(1);
#pragma unroll
            for (int jt = 0; jt < 4; ++jt) {
                const int j  = jt * 16 + l15;
                const int sw = (j & 7) << 3;
                f32x4 c = {};
#pragma unroll
                for (int kk = 0; kk < 2; ++kk) {
                    bf16x8 kf = *(const bf16x8*)&KL[cur][j][(kk * 32 + 8 * lg) ^ sw];
                    c = __builtin_amdgcn_mfma_f32_16x16x32_bf16(kf, qf[kk], c, 0, 0, 0);
                }
                s[jt] = c;
            }
            __builtin_amdgcn_s_setprio(0);

            if (kt == qtile) {
                const int qin = w * 16 + l15;
#pragma unroll
                for (int jt = 0; jt < 4; ++jt)
#pragma unroll
                    for (int r = 0; r < 4; ++r)
                        if (jt * 16 + 4 * lg + r > qin) s[jt][r] = NEG_MASK;
            }

            float t0 = m3(s[0][0], s[0][1], s[0][2]);
            float t1 = m3(s[0][3], s[1][0], s[1][1]);
            float t2 = m3(s[1][2], s[1][3], s[2][0]);
            float t3 = m3(s[2][1], s[2][2], s[2][3]);
            float t4 = m3(s[3][0], s[3][1], s[3][2]);
            float mxl = m3(m3(t0, t1, t2), m3(t3, t4, s[3][3]), NEG_MASK);

            if (__any(mxl > m_run + THRLOG2)) {
                float mx = fmaxf(mxl, __shfl_xor(mxl, 16));
                mx = fmaxf(mx, __shfl_xor(mx, 32));
                const float mt   = fmaxf(m_run, mx);
                const float corr = __builtin_amdgcn_exp2f(m_run - mt);
                l_part *= corr;
                m_run   = mt;
                float corr_a[4];
#pragma unroll
                for (int r = 0; r < 4; ++r) corr_a[r] = __shfl(corr, 4 * lg + r);
#pragma unroll
                for (int dt = 0; dt < 4; ++dt)
#pragma unroll
                    for (int r = 0; r < 4; ++r) acc[dt][r] *= corr_a[r];
            }

            float ps = 0.0f;
            float pe[4][4];
#pragma unroll
            for (int jt = 0; jt < 4; ++jt)
#pragma unroll
                for (int r = 0; r < 4; ++r) {
                    float e = __builtin_amdgcn_exp2f(s[jt][r] - m_run);
                    pe[jt][r] = e;
                    ps += e;
                }
            l_part += ps;

            bf16x8 pa[2];
#pragma unroll
            for (int kk = 0; kk < 2; ++kk)
#pragma unroll
                for (int i = 0; i < 4; ++i) {
                    pa[kk][i]     = (__bf16)pe[2 * kk][i];
                    pa[kk][4 + i] = (__bf16)pe[2 * kk + 1][i];
                }

            __builtin_amdgcn_s_setprio(1);
#pragma unroll
            for (int dt = 0; dt < 4; ++dt) {
                const int d  = dt * 16 + l15;
                const int sw = (d & 7) << 3;
#pragma unroll
                for (int kk = 0; kk < 2; ++kk) {
                    bf16x8 vb = *(const bf16x8*)&VL[cur][d][(kk * 32 + 8 * lg) ^ sw];
                    acc[dt] = __builtin_amdgcn_mfma_f32_16x16x32_bf16(pa[kk], vb, acc[dt], 0, 0, 0);
                }
            }
            __builtin_amdgcn_s_setprio(0);
        }

        float l_tot = l_part + __shfl_xor(l_part, 16);
        l_tot += __shfl_xor(l_tot, 32);
        float li_a[4];
#pragma unroll
        for (int r = 0; r < 4; ++r)
            li_a[r] = __builtin_amdgcn_rcpf(__shfl(l_tot, 4 * lg + r));
#pragma unroll
        for (int dt = 0; dt < 4; ++dt)
#pragma unroll
            for (int r = 0; r < 4; ++r)
                oh[(size_t)(qbase + w * 16 + 4 * lg + r) * D_DIM + dt * 16 + l15] =
                    acc[dt][r] * li_a[r];
    }
}
#undef STAGE

// ---------------- raw fallback (no-ws path) ----------------

#define PAD 72
__global__ __launch_bounds__(256)
void attn_fwd_fallback(const float* __restrict__ q, const float* __restrict__ k,
                       const float* __restrict__ v, float* __restrict__ out)
{
    __shared__ __bf16 Klds[64][PAD];
    __shared__ __bf16 Vt[D_DIM][PAD];
    __shared__ __bf16 Plds[4][16][PAD];

    const int tid  = threadIdx.x;
    const int w    = tid >> 6;
    const int lane = tid & 63;
    const int l15  = lane & 15;
    const int lg   = lane >> 4;

    const int qtile = blockIdx.x;
    const int bh    = blockIdx.y;
    const int qbase = qtile * 64;

    const size_t head_off = (size_t)bh * S_LEN * D_DIM;
    const float* qh = q + head_off;
    const float* kh = k + head_off;
    const float* vh = v + head_off;
    float*       oh = out + head_off;

    bf16x8 qf[2];
    {
        const int qrow = qbase + w * 16 + l15;
        const float* qp = qh + (size_t)qrow * D_DIM + 8 * lg;
#pragma unroll
        for (int c = 0; c < 2; ++c) {
            float4 a = *(const float4*)(qp + c * 32);
            float4 b = *(const float4*)(qp + c * 32 + 4);
            bf16x8 f;
            f[0] = (__bf16)(a.x * 0.125f); f[1] = (__bf16)(a.y * 0.125f);
            f[2] = (__bf16)(a.z * 0.125f); f[3] = (__bf16)(a.w * 0.125f);
            f[4] = (__bf16)(b.x * 0.125f); f[5] = (__bf16)(b.y * 0.125f);
            f[6] = (__bf16)(b.z * 0.125f); f[7] = (__bf16)(b.w * 0.125f);
            qf[c] = f;
        }
    }

    f32x4 acc[4] = {};
    float m_run[4], l_run[4];
#pragma unroll
    for (int r = 0; r < 4; ++r) { m_run[r] = -1e30f; l_run[r] = 0.0f; }

    const int nkv = qtile + 1;
    for (int kt = 0; kt < nkv; ++kt) {
        const int kv0 = kt * 64;
        __syncthreads();
#pragma unroll
        for (int it = 0; it < 4; ++it) {
            int idx = tid + it * 256;
            int row = idx >> 4;
            int c4  = idx & 15;
            float4 kf = *(const float4*)(kh + (size_t)(kv0 + row) * D_DIM + c4 * 4);
            __bf16* kd = &Klds[row][c4 * 4];
            kd[0] = (__bf16)kf.x; kd[1] = (__bf16)kf.y;
            kd[2] = (__bf16)kf.z; kd[3] = (__bf16)kf.w;
            float4 vf = *(const float4*)(vh + (size_t)(kv0 + row) * D_DIM + c4 * 4);
            Vt[c4 * 4 + 0][row] = (__bf16)vf.x;
            Vt[c4 * 4 + 1][row] = (__bf16)vf.y;
            Vt[c4 * 4 + 2][row] = (__bf16)vf.z;
            Vt[c4 * 4 + 3][row] = (__bf16)vf.w;
        }
        __syncthreads();

        f32x4 sfrag[4];
#pragma unroll
        for (int kc = 0; kc < 4; ++kc) {
            bf16x8 kf0 = *(const bf16x8*)&Klds[kc * 16 + l15][8 * lg];
            bf16x8 kf1 = *(const bf16x8*)&Klds[kc * 16 + l15][32 + 8 * lg];
            f32x4 c = {};
            c = __builtin_amdgcn_mfma_f32_16x16x32_bf16(qf[0], kf0, c, 0, 0, 0);
            c = __builtin_amdgcn_mfma_f32_16x16x32_bf16(qf[1], kf1, c, 0, 0, 0);
            sfrag[kc] = c;
        }

        if (kt == qtile) {
#pragma unroll
            for (int kc = 0; kc < 4; ++kc) {
                const int j = kv0 + kc * 16 + l15;
#pragma unroll
                for (int r = 0; r < 4; ++r) {
                    const int qrow = qbase + w * 16 + lg * 4 + r;
                    if (j > qrow) sfrag[kc][r] = -1e30f;
                }
            }
        }

        float mt[4], corr[4], ps[4];
#pragma unroll
        for (int r = 0; r < 4; ++r) {
            float mx = fmaxf(fmaxf(sfrag[0][r], sfrag[1][r]),
                             fmaxf(sfrag[2][r], sfrag[3][r]));
            mx = fmaxf(mx, __shfl_xor(mx, 1));
            mx = fmaxf(mx, __shfl_xor(mx, 2));
            mx = fmaxf(mx, __shfl_xor(mx, 4));
            mx = fmaxf(mx, __shfl_xor(mx, 8));
            mt[r]   = fmaxf(m_run[r], mx);
            corr[r] = __expf(m_run[r] - mt[r]);
            ps[r]   = 0.0f;
        }
#pragma unroll
        for (int kc = 0; kc < 4; ++kc) {
#pragma unroll
            for (int r = 0; r < 4; ++r) {
                float pp = __expf(sfrag[kc][r] - mt[r]);
                ps[r] += pp;
                Plds[w][lg * 4 + r][kc * 16 + l15] = (__bf16)pp;
            }
        }
#pragma unroll
        for (int r = 0; r < 4; ++r) {
            ps[r] += __shfl_xor(ps[r], 1);
            ps[r] += __shfl_xor(ps[r], 2);
            ps[r] += __shfl_xor(ps[r], 4);
            ps[r] += __shfl_xor(ps[r], 8);
            l_run[r] = l_run[r] * corr[r] + ps[r];
            m_run[r] = mt[r];
        }
#pragma unroll
        for (int dt = 0; dt < 4; ++dt)
#pragma unroll
            for (int r = 0; r < 4; ++r)
                acc[dt][r] *= corr[r];

#pragma unroll
        for (int kk = 0; kk < 2; ++kk) {
            bf16x8 pf = *(const bf16x8*)&Plds[w][l15][kk * 32 + 8 * lg];
#pragma unroll
            for (int dt = 0; dt < 4; ++dt) {
                bf16x8 vf = *(const bf16x8*)&Vt[dt * 16 + l15][kk * 32 + 8 * lg];
                acc[dt] = __builtin_amdgcn_mfma_f32_16x16x32_bf16(pf, vf, acc[dt], 0, 0, 0);
            }
        }
    }

#pragma unroll
    for (int dt = 0; dt < 4; ++dt) {
#pragma unroll
        for (int r = 0; r < 4; ++r) {
            const int qrow = qbase + w * 16 + lg * 4 + r;
            oh[(size_t)qrow * D_DIM + dt * 16 + l15] = acc[dt][r] / l_run[r];
        }
    }
}

extern "C" void kernel_launch(void* const* d_in, const int* in_sizes, int n_in,
                              void* d_out, int out_size, void* d_ws, size_t ws_size,
                              hipStream_t stream) {
    const float* q = (const float*)d_in[0];
    const float* k = (const float*)d_in[1];
    const float* v = (const float*)d_in[2];
    float* out = (float*)d_out;

    const size_t kv_elems   = (size_t)NBH * S_LEN * D_DIM;          // 4,194,304
    const size_t conv_bytes = kv_elems * 2 * sizeof(__bf16);        // 16 MiB
    const size_t op_bytes   = (size_t)NBH * NT128 * 2 * 8192 * 2;   // 16 MiB (bf16)
    const size_t ml_bytes   = (size_t)NBH * NT128 * 2 * 256 * 4;    // 1 MiB

    if (ws_size >= conv_bytes + op_bytes + ml_bytes) {
        __bf16* kb = (__bf16*)d_ws;
        __bf16* vt = kb + kv_elems;
        __bf16* opart = (__bf16*)((char*)d_ws + conv_bytes);
        float*  ml    = (float*)((char*)d_ws + conv_bytes + op_bytes);
        conv_fused_kernel<<<dim3(S_LEN / 64, NBH), dim3(256), 0, stream>>>(k, v, kb, vt);
        attn_fwd_split<<<dim3(16, NBH), dim3(256), 0, stream>>>(q, kb, vt, opart, ml);
        combine_kernel<<<dim3(NT128, NBH), dim3(256), 0, stream>>>(opart, ml, out);
    } else if (ws_size >= conv_bytes) {
        __bf16* kb = (__bf16*)d_ws;
        __bf16* vt = kb + kv_elems;
        conv_fused_kernel<<<dim3(S_LEN / 64, NBH), dim3(256), 0, stream>>>(k, v, kb, vt);
        attn_fwd_glds<<<dim3(16, NBH), dim3(256), 0, stream>>>(q, kb, vt, out);
    } else {
        attn_fwd_fallback<<<dim3(S_LEN / 64, NBH), dim3(256), 0, stream>>>(q, k, v, out);
    }
}